// Round 6
// baseline (198.660 us; speedup 1.0000x reference)
//
#include <hip/hip_runtime.h>
#include <cstdint>

#define N 4096
#define D 1024
#define KC_COUNT (D / 32)   // 32 k-chunks of 32
#define TB (N / 128)        // 32 tile-blocks per dim
#define NBLK (TB * (TB + 1) / 2)   // 528 upper-triangular block pairs

typedef _Float16 f16;
typedef __attribute__((ext_vector_type(4))) _Float16 f16x4;
typedef __attribute__((ext_vector_type(8))) _Float16 f16x8;
typedef __attribute__((ext_vector_type(4))) float f32x4;

// Monotone map fp32 -> u32 so unsigned compare == float compare (ascending).
__device__ __forceinline__ unsigned int orderable(float f) {
    unsigned int b = __float_as_uint(f);
    return (b & 0x80000000u) ? ~b : (b | 0x80000000u);
}

__device__ __forceinline__ void async_copy16(const f16* g, f16* l) {
    __builtin_amdgcn_global_load_lds(
        (const __attribute__((address_space(1))) uint32_t*)(const void*)g,
        (__attribute__((address_space(3))) uint32_t*)(void*)l,
        16 /*bytes*/, 0 /*offset*/, 0 /*aux*/);
}

// Split fp32 X into f16 hi/lo planes pre-swizzled into MFMA fragment order:
// chunk (rg, kc, hl) holds 512 f16 ordered by lane = (q<<4)|m, elem = k&7,
// where row = rg*16+m, k = kc*32+q*8+elem.
// Coalesced read -> LDS row-major -> coalesced swizzled store.
// ROW_PAD=8: stride 1032 f16 = 2064 B == 0 mod 16, so the b128 phase-2 reads
// stay 16B-aligned (ROW_PAD=4 gave 2056 B -> misaligned ds_read_b128 -> fault).
#define ROW_PAD 8
#define ROW_STRIDE (D + ROW_PAD)
__global__ __launch_bounds__(256) void split_swizzle(
    const float* __restrict__ X, f16* __restrict__ Xsw,
    unsigned long long* __restrict__ keys)
{
    __shared__ f16 Hs[16 * ROW_STRIDE];
    __shared__ f16 Ls[16 * ROW_STRIDE];
    const int tid = threadIdx.x;
    const int rg = blockIdx.x;                 // 0..255, 16 rows each
    if (tid < 32) keys[rg * 32 + tid] = 0xFFFFFFFFFFFFFFFFull;

    const float4* src = (const float4*)(X + (size_t)rg * 16 * D);
#pragma unroll
    for (int it = 0; it < 16; ++it) {
        const int idx4 = it * 256 + tid;       // 0..4095 float4 slots
        const int row = idx4 >> 8;
        const int k4 = (idx4 & 255) * 4;
        const float4 v = src[idx4];
        const float xs[4] = {v.x, v.y, v.z, v.w};
        f16x4 h, l;
#pragma unroll
        for (int i = 0; i < 4; ++i) {
            f16 hh = (f16)xs[i];
            h[i] = hh;
            l[i] = (f16)(xs[i] - (float)hh);
        }
        *(f16x4*)(Hs + row * ROW_STRIDE + k4) = h;
        *(f16x4*)(Ls + row * ROW_STRIDE + k4) = l;
    }
    __syncthreads();
#pragma unroll
    for (int hl = 0; hl < 2; ++hl) {
        const f16* lds = hl ? Ls : Hs;
#pragma unroll
        for (int it = 0; it < 8; ++it) {
            const int o = it * 256 + tid;      // uint4 slot among 2048
            const int kc = o >> 6, lo_ = o & 63;
            const int q = lo_ >> 4, m = lo_ & 15;
            const uint4 v = *(const uint4*)(lds + m * ROW_STRIDE + kc * 32 + q * 8);
            *(uint4*)(Xsw + (((size_t)rg * KC_COUNT + kc) * 2 + hl) * 512 + lo_ * 8) = v;
        }
    }
}

// Upper-triangular 128x128 tile of dist = X @ X^T via f16-split MFMA
// (hi*hi + hi*lo + lo*hi). Double-buffered LDS, ONE barrier per kc step:
// prefetch kc+1 while computing kc; the vmcnt(0) drain at the barrier waits
// on loads that already had the whole compute phase to land.
__global__ __launch_bounds__(256) void gemm_argmin_sym(
    const f16* __restrict__ Xsw, const int* __restrict__ labels,
    unsigned long long* __restrict__ keys_ap,
    unsigned long long* __restrict__ keys_an)
{
    __shared__ f16 As[2][8 * 2 * 512];   // [buf][rgLocal(8)][hl(2)][lane(64)][8] = 2x16 KB
    __shared__ f16 Bs[2][8 * 2 * 512];   // 2x16 KB  (total 64 KB)

    // Decode linear block id -> (bi, bj) with bi <= bj.
    int r = blockIdx.x, bi = 0;
    while (r >= TB - bi) { r -= TB - bi; ++bi; }
    const int bj = bi + r;

    const int tid = threadIdx.x;
    const int lane = tid & 63;
    const int w = tid >> 6;            // wave 0..3
    const int wr = w >> 1, wc = w & 1; // 2x2 wave grid, 64x64 region each
    const int rowBase = bi * 128, colBase = bj * 128;

    f32x4 acc[4][4];
#pragma unroll
    for (int mi = 0; mi < 4; ++mi)
#pragma unroll
        for (int ni = 0; ni < 4; ++ni) acc[mi][ni] = (f32x4){0.f, 0.f, 0.f, 0.f};

    // Wave w stages loads L = w*8 .. w*8+7 (32 total: A/B x 8rg x hi/lo)
    const f16* g[8];
    f16* lp0[8];
    f16* lp1[8];
#pragma unroll
    for (int j = 0; j < 8; ++j) {
        int L = w * 8 + j;
        int isB = L >> 4, rem = L & 15, rgL = rem >> 1, hl = rem & 1;
        int rgG = (isB ? bj : bi) * 8 + rgL;
        g[j] = Xsw + ((((size_t)rgG * KC_COUNT) * 2 + hl) * 64 + lane) * 8;  // kc=0
        lp0[j] = (isB ? Bs[0] : As[0]) + (rgL * 2 + hl) * 512;
        lp1[j] = (isB ? Bs[1] : As[1]) + (rgL * 2 + hl) * 512;
    }

    // Prologue: stage kc=0 into buf0.
#pragma unroll
    for (int j = 0; j < 8; ++j) async_copy16(g[j], lp0[j]);
    __syncthreads();

    for (int kc = 0; kc < KC_COUNT; ++kc) {
        const int cur = kc & 1;
        if (kc + 1 < KC_COUNT) {   // prefetch next tile into the other buffer
#pragma unroll
            for (int j = 0; j < 8; ++j)
                async_copy16(g[j] + (size_t)(kc + 1) * 1024, cur ? lp0[j] : lp1[j]);
        }

        const f16* A_ = As[cur];
        const f16* B_ = Bs[cur];
        f16x8 ah[4], al[4], bh[4], bl[4];
#pragma unroll
        for (int t2 = 0; t2 < 4; ++t2) {
            int rgA = wr * 4 + t2, rgB = wc * 4 + t2;
            ah[t2] = *(const f16x8*)(A_ + (rgA * 2 + 0) * 512 + lane * 8);
            al[t2] = *(const f16x8*)(A_ + (rgA * 2 + 1) * 512 + lane * 8);
            bh[t2] = *(const f16x8*)(B_ + (rgB * 2 + 0) * 512 + lane * 8);
            bl[t2] = *(const f16x8*)(B_ + (rgB * 2 + 1) * 512 + lane * 8);
        }
#pragma unroll
        for (int mi = 0; mi < 4; ++mi)
#pragma unroll
            for (int ni = 0; ni < 4; ++ni) {
                acc[mi][ni] = __builtin_amdgcn_mfma_f32_16x16x32_f16(
                    ah[mi], bh[ni], acc[mi][ni], 0, 0, 0);
                acc[mi][ni] = __builtin_amdgcn_mfma_f32_16x16x32_f16(
                    ah[mi], bl[ni], acc[mi][ni], 0, 0, 0);
                acc[mi][ni] = __builtin_amdgcn_mfma_f32_16x16x32_f16(
                    al[mi], bh[ni], acc[mi][ni], 0, 0, 0);
            }
        __syncthreads();   // reads of cur done; prefetch into nxt drained
    }

    // Epilogue. C/D layout (16x16): col = lane&15, row = (lane>>4)*4 + reg.
    const int g16 = lane >> 4, c16 = lane & 15;

    // Label values (L2-hot; same-address within lane groups -> cheap).
    int ljv[4], liv[4][4];
#pragma unroll
    for (int ni = 0; ni < 4; ++ni) ljv[ni] = labels[colBase + wc * 64 + ni * 16 + c16];
#pragma unroll
    for (int mi = 0; mi < 4; ++mi)
#pragma unroll
        for (int reg = 0; reg < 4; ++reg)
            liv[mi][reg] = labels[rowBase + wr * 64 + mi * 16 + g16 * 4 + reg];

    // Pass 1: row-side argmin (rows of bi-range over cols of bj-range).
#pragma unroll
    for (int mi = 0; mi < 4; ++mi) {
#pragma unroll
        for (int reg = 0; reg < 4; ++reg) {
            const int rloc = wr * 64 + mi * 16 + g16 * 4 + reg;
            const int i = rowBase + rloc;
            const int li = liv[mi][reg];
            float bestAp = __builtin_huge_valf(); int jAp = 0;
            float bestAn = __builtin_huge_valf(); int jAn = 0;
#pragma unroll
            for (int ni = 0; ni < 4; ++ni) {
                const int jcol = colBase + wc * 64 + ni * 16 + c16;
                const float v = acc[mi][ni][reg];
                const bool same = (li == ljv[ni]);
                const float vap = (same && (i != jcol)) ? v : v + 2.0f;
                const float van = (!same) ? v : v + 2.0f;
                if (vap < bestAp) { bestAp = vap; jAp = jcol; }
                if (van < bestAn) { bestAn = van; jAn = jcol; }
            }
            unsigned long long kap =
                ((unsigned long long)orderable(bestAp) << 32) | (unsigned)jAp;
            unsigned long long kan =
                ((unsigned long long)orderable(bestAn) << 32) | (unsigned)jAn;
#pragma unroll
            for (int off = 1; off < 16; off <<= 1) {
                unsigned long long o = __shfl_xor(kap, off); kap = o < kap ? o : kap;
                o = __shfl_xor(kan, off); kan = o < kan ? o : kan;
            }
            if (c16 == 0) {
                atomicMin(&keys_ap[i], kap);
                atomicMin(&keys_an[i], kan);
            }
        }
    }

    // Pass 2 (off-diagonal only): column-side argmin via symmetry —
    // rows of bj-range get candidates with index in bi-range.
    if (bi != bj) {
#pragma unroll
        for (int ni = 0; ni < 4; ++ni) {
            const int j = colBase + wc * 64 + ni * 16 + c16;
            const int lj = ljv[ni];
            float bestAp = __builtin_huge_valf(); int iAp = 0;
            float bestAn = __builtin_huge_valf(); int iAn = 0;
#pragma unroll
            for (int mi = 0; mi < 4; ++mi)
#pragma unroll
                for (int reg = 0; reg < 4; ++reg) {
                    const int i = rowBase + wr * 64 + mi * 16 + g16 * 4 + reg;
                    const float v = acc[mi][ni][reg];
                    const bool same = (liv[mi][reg] == lj);
                    const float vap = same ? v : v + 2.0f;   // i != j off-diag
                    const float van = (!same) ? v : v + 2.0f;
                    if (vap < bestAp) { bestAp = vap; iAp = i; }
                    if (van < bestAn) { bestAn = van; iAn = i; }
                }
            unsigned long long kap =
                ((unsigned long long)orderable(bestAp) << 32) | (unsigned)iAp;
            unsigned long long kan =
                ((unsigned long long)orderable(bestAn) << 32) | (unsigned)iAn;
            // Reduce over g16 (lane bits 4,5): lanes sharing c16 share j.
#pragma unroll
            for (int off = 16; off < 64; off <<= 1) {
                unsigned long long o = __shfl_xor(kap, off); kap = o < kap ? o : kap;
                o = __shfl_xor(kan, off); kan = o < kan ? o : kan;
            }
            if (g16 == 0) {
                atomicMin(&keys_ap[j], kap);
                atomicMin(&keys_an[j], kan);
            }
        }
    }
}

__global__ void gather_rows(const float* __restrict__ A,
                            const unsigned long long* __restrict__ keys_ap,
                            const unsigned long long* __restrict__ keys_an,
                            float* __restrict__ out)
{
    const int row = blockIdx.x;
    const int t = threadIdx.x;
    const int ja = (int)(keys_ap[row] & 0xFFFFFFFFull);
    const int jn = (int)(keys_an[row] & 0xFFFFFFFFull);
    const float4* Av = (const float4*)A;
    float4* Ov = (float4*)out;
    Ov[(size_t)row * (D / 4) + t]       = Av[(size_t)ja * (D / 4) + t];
    Ov[(size_t)(N + row) * (D / 4) + t] = Av[(size_t)jn * (D / 4) + t];
}

extern "C" void kernel_launch(void* const* d_in, const int* in_sizes, int n_in,
                              void* d_out, int out_size, void* d_ws, size_t ws_size,
                              hipStream_t stream) {
    const float* A = (const float*)d_in[0];
    const int* labels = (const int*)d_in[1];  // integer inputs arrive as int32
    float* out = (float*)d_out;

    unsigned long long* keys = (unsigned long long*)d_ws;          // 64 KB
    f16* Xsw = (f16*)((char*)d_ws + 65536);                        // 16 MB hi+lo

    split_swizzle<<<N / 16, 256, 0, stream>>>(A, Xsw, keys);
    gemm_argmin_sym<<<NBLK, 256, 0, stream>>>(Xsw, labels, keys, keys + N);
    gather_rows<<<N, 256, 0, stream>>>(A, keys, keys + N, out);
}

// Round 7
// 187.132 us; speedup vs baseline: 1.0616x; 1.0616x over previous
//
#include <hip/hip_runtime.h>
#include <cstdint>

#define N 4096
#define D 1024
#define KC_COUNT (D / 32)   // 32 k-chunks of 32
#define TB (N / 128)        // 32 tile-blocks per dim
#define NBLK (TB * (TB + 1) / 2)   // 528 upper-triangular block pairs

typedef _Float16 f16;
typedef __attribute__((ext_vector_type(4))) _Float16 f16x4;
typedef __attribute__((ext_vector_type(8))) _Float16 f16x8;
typedef __attribute__((ext_vector_type(4))) float f32x4;

// Monotone map fp32 -> u32 so unsigned compare == float compare (ascending).
__device__ __forceinline__ unsigned int orderable(float f) {
    unsigned int b = __float_as_uint(f);
    return (b & 0x80000000u) ? ~b : (b | 0x80000000u);
}

__device__ __forceinline__ void async_copy16(const f16* g, f16* l) {
    __builtin_amdgcn_global_load_lds(
        (const __attribute__((address_space(1))) uint32_t*)(const void*)g,
        (__attribute__((address_space(3))) uint32_t*)(void*)l,
        16 /*bytes*/, 0 /*offset*/, 0 /*aux*/);
}

// Split fp32 X into f16 hi/lo planes pre-swizzled into MFMA fragment order.
// ROW_PAD=8: stride 2064 B == 0 mod 16 keeps phase-2 ds_read_b128 aligned.
#define ROW_PAD 8
#define ROW_STRIDE (D + ROW_PAD)
__global__ __launch_bounds__(256) void split_swizzle(
    const float* __restrict__ X, f16* __restrict__ Xsw,
    unsigned long long* __restrict__ keys)
{
    __shared__ f16 Hs[16 * ROW_STRIDE];
    __shared__ f16 Ls[16 * ROW_STRIDE];
    const int tid = threadIdx.x;
    const int rg = blockIdx.x;                 // 0..255, 16 rows each
    if (tid < 32) keys[rg * 32 + tid] = 0xFFFFFFFFFFFFFFFFull;

    const float4* src = (const float4*)(X + (size_t)rg * 16 * D);
#pragma unroll
    for (int it = 0; it < 16; ++it) {
        const int idx4 = it * 256 + tid;       // 0..4095 float4 slots
        const int row = idx4 >> 8;
        const int k4 = (idx4 & 255) * 4;
        const float4 v = src[idx4];
        const float xs[4] = {v.x, v.y, v.z, v.w};
        f16x4 h, l;
#pragma unroll
        for (int i = 0; i < 4; ++i) {
            f16 hh = (f16)xs[i];
            h[i] = hh;
            l[i] = (f16)(xs[i] - (float)hh);
        }
        *(f16x4*)(Hs + row * ROW_STRIDE + k4) = h;
        *(f16x4*)(Ls + row * ROW_STRIDE + k4) = l;
    }
    __syncthreads();
#pragma unroll
    for (int hl = 0; hl < 2; ++hl) {
        const f16* lds = hl ? Ls : Hs;
#pragma unroll
        for (int it = 0; it < 8; ++it) {
            const int o = it * 256 + tid;      // uint4 slot among 2048
            const int kc = o >> 6, lo_ = o & 63;
            const int q = lo_ >> 4, m = lo_ & 15;
            const uint4 v = *(const uint4*)(lds + m * ROW_STRIDE + kc * 32 + q * 8);
            *(uint4*)(Xsw + (((size_t)rg * KC_COUNT + kc) * 2 + hl) * 512 + lo_ * 8) = v;
        }
    }
}

// Upper-triangular 128x128 tile of dist = X @ X^T via f16-split MFMA
// (hi*hi + hi*lo + lo*hi). Double-buffered LDS, ONE barrier per kc step,
// placed BEFORE the prefetch issue: the barrier's implicit vmcnt(0) drain
// then only waits on loads issued one full compute phase earlier (landed),
// and the fresh prefetch stays in flight across the compute phase.
__global__ __launch_bounds__(256) void gemm_argmin_sym(
    const f16* __restrict__ Xsw, const int* __restrict__ labels,
    unsigned long long* __restrict__ keys_ap,
    unsigned long long* __restrict__ keys_an)
{
    __shared__ f16 As[2][8 * 2 * 512];   // [buf][rgLocal(8)][hl(2)][lane(64)][8] = 2x16 KB
    __shared__ f16 Bs[2][8 * 2 * 512];   // 2x16 KB  (total 64 KB)

    // Decode linear block id -> (bi, bj) with bi <= bj.
    int r = blockIdx.x, bi = 0;
    while (r >= TB - bi) { r -= TB - bi; ++bi; }
    const int bj = bi + r;

    const int tid = threadIdx.x;
    const int lane = tid & 63;
    const int w = tid >> 6;            // wave 0..3
    const int wr = w >> 1, wc = w & 1; // 2x2 wave grid, 64x64 region each
    const int rowBase = bi * 128, colBase = bj * 128;

    f32x4 acc[4][4];
#pragma unroll
    for (int mi = 0; mi < 4; ++mi)
#pragma unroll
        for (int ni = 0; ni < 4; ++ni) acc[mi][ni] = (f32x4){0.f, 0.f, 0.f, 0.f};

    // Wave w stages loads L = w*8 .. w*8+7 (32 total: A/B x 8rg x hi/lo)
    const f16* g[8];
    f16* lp0[8];
    f16* lp1[8];
#pragma unroll
    for (int j = 0; j < 8; ++j) {
        int L = w * 8 + j;
        int isB = L >> 4, rem = L & 15, rgL = rem >> 1, hl = rem & 1;
        int rgG = (isB ? bj : bi) * 8 + rgL;
        g[j] = Xsw + ((((size_t)rgG * KC_COUNT) * 2 + hl) * 64 + lane) * 8;  // kc=0
        lp0[j] = (isB ? Bs[0] : As[0]) + (rgL * 2 + hl) * 512;
        lp1[j] = (isB ? Bs[1] : As[1]) + (rgL * 2 + hl) * 512;
    }

    // Prologue: stage kc=0 into buf0 (drained by the loop's first barrier).
#pragma unroll
    for (int j = 0; j < 8; ++j) async_copy16(g[j], lp0[j]);

    for (int kc = 0; kc < KC_COUNT; ++kc) {
        const int cur = kc & 1;
        __syncthreads();   // drains prev-iteration loads (latency covered by
                           // prev compute); buf[nxt] safe to overwrite.
        if (kc + 1 < KC_COUNT) {   // prefetch next tile into the other buffer
#pragma unroll
            for (int j = 0; j < 8; ++j)
                async_copy16(g[j] + (size_t)(kc + 1) * 1024, cur ? lp0[j] : lp1[j]);
        }

        const f16* A_ = As[cur];
        const f16* B_ = Bs[cur];
        f16x8 ah[4], al[4], bh[4], bl[4];
#pragma unroll
        for (int t2 = 0; t2 < 4; ++t2) {
            int rgA = wr * 4 + t2, rgB = wc * 4 + t2;
            ah[t2] = *(const f16x8*)(A_ + (rgA * 2 + 0) * 512 + lane * 8);
            al[t2] = *(const f16x8*)(A_ + (rgA * 2 + 1) * 512 + lane * 8);
            bh[t2] = *(const f16x8*)(B_ + (rgB * 2 + 0) * 512 + lane * 8);
            bl[t2] = *(const f16x8*)(B_ + (rgB * 2 + 1) * 512 + lane * 8);
        }
#pragma unroll
        for (int mi = 0; mi < 4; ++mi)
#pragma unroll
            for (int ni = 0; ni < 4; ++ni) {
                acc[mi][ni] = __builtin_amdgcn_mfma_f32_16x16x32_f16(
                    ah[mi], bh[ni], acc[mi][ni], 0, 0, 0);
                acc[mi][ni] = __builtin_amdgcn_mfma_f32_16x16x32_f16(
                    ah[mi], bl[ni], acc[mi][ni], 0, 0, 0);
                acc[mi][ni] = __builtin_amdgcn_mfma_f32_16x16x32_f16(
                    al[mi], bh[ni], acc[mi][ni], 0, 0, 0);
            }
        // no trailing barrier: next iteration's top barrier provides it;
        // epilogue touches no LDS.
    }

    // Epilogue. C/D layout (16x16): col = lane&15, row = (lane>>4)*4 + reg.
    const int g16 = lane >> 4, c16 = lane & 15;

    int ljv[4], liv[4][4];
#pragma unroll
    for (int ni = 0; ni < 4; ++ni) ljv[ni] = labels[colBase + wc * 64 + ni * 16 + c16];
#pragma unroll
    for (int mi = 0; mi < 4; ++mi)
#pragma unroll
        for (int reg = 0; reg < 4; ++reg)
            liv[mi][reg] = labels[rowBase + wr * 64 + mi * 16 + g16 * 4 + reg];

    // Pass 1: row-side argmin (rows of bi-range over cols of bj-range).
#pragma unroll
    for (int mi = 0; mi < 4; ++mi) {
#pragma unroll
        for (int reg = 0; reg < 4; ++reg) {
            const int rloc = wr * 64 + mi * 16 + g16 * 4 + reg;
            const int i = rowBase + rloc;
            const int li = liv[mi][reg];
            float bestAp = __builtin_huge_valf(); int jAp = 0;
            float bestAn = __builtin_huge_valf(); int jAn = 0;
#pragma unroll
            for (int ni = 0; ni < 4; ++ni) {
                const int jcol = colBase + wc * 64 + ni * 16 + c16;
                const float v = acc[mi][ni][reg];
                const bool same = (li == ljv[ni]);
                const float vap = (same && (i != jcol)) ? v : v + 2.0f;
                const float van = (!same) ? v : v + 2.0f;
                if (vap < bestAp) { bestAp = vap; jAp = jcol; }
                if (van < bestAn) { bestAn = van; jAn = jcol; }
            }
            unsigned long long kap =
                ((unsigned long long)orderable(bestAp) << 32) | (unsigned)jAp;
            unsigned long long kan =
                ((unsigned long long)orderable(bestAn) << 32) | (unsigned)jAn;
#pragma unroll
            for (int off = 1; off < 16; off <<= 1) {
                unsigned long long o = __shfl_xor(kap, off); kap = o < kap ? o : kap;
                o = __shfl_xor(kan, off); kan = o < kan ? o : kan;
            }
            if (c16 == 0) {
                atomicMin(&keys_ap[i], kap);
                atomicMin(&keys_an[i], kan);
            }
        }
    }

    // Pass 2 (off-diagonal only): column-side argmin via symmetry.
    if (bi != bj) {
#pragma unroll
        for (int ni = 0; ni < 4; ++ni) {
            const int j = colBase + wc * 64 + ni * 16 + c16;
            const int lj = ljv[ni];
            float bestAp = __builtin_huge_valf(); int iAp = 0;
            float bestAn = __builtin_huge_valf(); int iAn = 0;
#pragma unroll
            for (int mi = 0; mi < 4; ++mi)
#pragma unroll
                for (int reg = 0; reg < 4; ++reg) {
                    const int i = rowBase + wr * 64 + mi * 16 + g16 * 4 + reg;
                    const float v = acc[mi][ni][reg];
                    const bool same = (liv[mi][reg] == lj);
                    const float vap = same ? v : v + 2.0f;   // i != j off-diag
                    const float van = (!same) ? v : v + 2.0f;
                    if (vap < bestAp) { bestAp = vap; iAp = i; }
                    if (van < bestAn) { bestAn = van; iAn = i; }
                }
            unsigned long long kap =
                ((unsigned long long)orderable(bestAp) << 32) | (unsigned)iAp;
            unsigned long long kan =
                ((unsigned long long)orderable(bestAn) << 32) | (unsigned)iAn;
            // Reduce over g16 (lane bits 4,5): lanes sharing c16 share j.
#pragma unroll
            for (int off = 16; off < 64; off <<= 1) {
                unsigned long long o = __shfl_xor(kap, off); kap = o < kap ? o : kap;
                o = __shfl_xor(kan, off); kan = o < kan ? o : kan;
            }
            if (g16 == 0) {
                atomicMin(&keys_ap[j], kap);
                atomicMin(&keys_an[j], kan);
            }
        }
    }
}

__global__ void gather_rows(const float* __restrict__ A,
                            const unsigned long long* __restrict__ keys_ap,
                            const unsigned long long* __restrict__ keys_an,
                            float* __restrict__ out)
{
    const int row = blockIdx.x;
    const int t = threadIdx.x;
    const int ja = (int)(keys_ap[row] & 0xFFFFFFFFull);
    const int jn = (int)(keys_an[row] & 0xFFFFFFFFull);
    const float4* Av = (const float4*)A;
    float4* Ov = (float4*)out;
    Ov[(size_t)row * (D / 4) + t]       = Av[(size_t)ja * (D / 4) + t];
    Ov[(size_t)(N + row) * (D / 4) + t] = Av[(size_t)jn * (D / 4) + t];
}

extern "C" void kernel_launch(void* const* d_in, const int* in_sizes, int n_in,
                              void* d_out, int out_size, void* d_ws, size_t ws_size,
                              hipStream_t stream) {
    const float* A = (const float*)d_in[0];
    const int* labels = (const int*)d_in[1];  // integer inputs arrive as int32
    float* out = (float*)d_out;

    unsigned long long* keys = (unsigned long long*)d_ws;          // 64 KB
    f16* Xsw = (f16*)((char*)d_ws + 65536);                        // 16 MB hi+lo

    split_swizzle<<<N / 16, 256, 0, stream>>>(A, Xsw, keys);
    gemm_argmin_sym<<<NBLK, 256, 0, stream>>>(Xsw, labels, keys, keys + N);
    gather_rows<<<N, 256, 0, stream>>>(A, keys, keys + N, out);
}

// Round 8
// 177.266 us; speedup vs baseline: 1.1207x; 1.0557x over previous
//
#include <hip/hip_runtime.h>
#include <cstdint>

#define N 4096
#define D 1024
#define KC_COUNT (D / 32)   // 32 k-chunks of 32
#define TB (N / 128)        // 32 tile-blocks per dim
#define NBLK (TB * (TB + 1) / 2)   // 528 upper-triangular block pairs

typedef _Float16 f16;
typedef __attribute__((ext_vector_type(4))) _Float16 f16x4;
typedef __attribute__((ext_vector_type(8))) _Float16 f16x8;
typedef __attribute__((ext_vector_type(4))) float f32x4;

// Monotone map fp32 -> u32 so unsigned compare == float compare (ascending).
__device__ __forceinline__ unsigned int orderable(float f) {
    unsigned int b = __float_as_uint(f);
    return (b & 0x80000000u) ? ~b : (b | 0x80000000u);
}

// Split fp32 X into f16 hi/lo planes pre-swizzled into MFMA fragment order:
// chunk (rg, kc, hl) holds 512 f16 ordered by lane=(q<<4)|m, elem=k&7, where
// row = rg*16+m, k = kc*32+q*8+elem. A lane's fragment = contiguous 16 B.
#define ROW_PAD 8
#define ROW_STRIDE (D + ROW_PAD)   // 2064 B rows: keeps ds_read_b128 aligned
__global__ __launch_bounds__(256) void split_swizzle(
    const float* __restrict__ X, f16* __restrict__ Xsw,
    unsigned long long* __restrict__ keys)
{
    __shared__ f16 Hs[16 * ROW_STRIDE];
    __shared__ f16 Ls[16 * ROW_STRIDE];
    const int tid = threadIdx.x;
    const int rg = blockIdx.x;                 // 0..255, 16 rows each
    if (tid < 32) keys[rg * 32 + tid] = 0xFFFFFFFFFFFFFFFFull;

    const float4* src = (const float4*)(X + (size_t)rg * 16 * D);
#pragma unroll
    for (int it = 0; it < 16; ++it) {
        const int idx4 = it * 256 + tid;       // 0..4095 float4 slots
        const int row = idx4 >> 8;
        const int k4 = (idx4 & 255) * 4;
        const float4 v = src[idx4];
        const float xs[4] = {v.x, v.y, v.z, v.w};
        f16x4 h, l;
#pragma unroll
        for (int i = 0; i < 4; ++i) {
            f16 hh = (f16)xs[i];
            h[i] = hh;
            l[i] = (f16)(xs[i] - (float)hh);
        }
        *(f16x4*)(Hs + row * ROW_STRIDE + k4) = h;
        *(f16x4*)(Ls + row * ROW_STRIDE + k4) = l;
    }
    __syncthreads();
#pragma unroll
    for (int hl = 0; hl < 2; ++hl) {
        const f16* lds = hl ? Ls : Hs;
#pragma unroll
        for (int it = 0; it < 8; ++it) {
            const int o = it * 256 + tid;      // uint4 slot among 2048
            const int kc = o >> 6, lo_ = o & 63;
            const int q = lo_ >> 4, m = lo_ & 15;
            const uint4 v = *(const uint4*)(lds + m * ROW_STRIDE + kc * 32 + q * 8);
            *(uint4*)(Xsw + (((size_t)rg * KC_COUNT + kc) * 2 + hl) * 512 + lo_ * 8) = v;
        }
    }
}

// Upper-triangular 128x128 tile of dist = X @ X^T via f16-split MFMA
// (hi*hi + hi*lo + lo*hi). NO LDS, NO barriers in the K-loop: fragments are
// loaded straight from the pre-swizzled global layout into VGPRs, register
// double-buffered (unroll-2 ping-pong). Compiler emits fine-grained vmcnt
// waits; loads for kc+1 are in flight across the whole MFMA phase of kc.
__global__ __launch_bounds__(256) void gemm_argmin_sym(
    const f16* __restrict__ Xsw, const int* __restrict__ labels,
    unsigned long long* __restrict__ keys_ap,
    unsigned long long* __restrict__ keys_an)
{
    // Decode linear block id -> (bi, bj) with bi <= bj.
    int r = blockIdx.x, bi = 0;
    while (r >= TB - bi) { r -= TB - bi; ++bi; }
    const int bj = bi + r;

    const int tid = threadIdx.x;
    const int lane = tid & 63;
    const int w = tid >> 6;            // wave 0..3
    const int wr = w >> 1, wc = w & 1; // 2x2 wave grid, 64x64 region each
    const int rowBase = bi * 128, colBase = bj * 128;

    f32x4 acc[4][4];
#pragma unroll
    for (int mi = 0; mi < 4; ++mi)
#pragma unroll
        for (int ni = 0; ni < 4; ++ni) acc[mi][ni] = (f32x4){0.f, 0.f, 0.f, 0.f};

    // Per-wave fragment base pointers (hi at +0, lo at +512; kc stride 1024 f16).
    const f16* baseA[4];
    const f16* baseB[4];
#pragma unroll
    for (int t2 = 0; t2 < 4; ++t2) {
        const int rgA = bi * 8 + wr * 4 + t2;
        const int rgB = bj * 8 + wc * 4 + t2;
        baseA[t2] = Xsw + ((size_t)rgA * KC_COUNT * 2) * 512 + lane * 8;
        baseB[t2] = Xsw + ((size_t)rgB * KC_COUNT * 2) * 512 + lane * 8;
    }

    f16x8 ah0[4], al0[4], bh0[4], bl0[4];   // ping
    f16x8 ah1[4], al1[4], bh1[4], bl1[4];   // pong

#define LOAD_SET(AH, AL, BH, BL, KC_) \
    _Pragma("unroll") \
    for (int t2 = 0; t2 < 4; ++t2) { \
        const f16* pa = baseA[t2] + (size_t)(KC_) * 1024; \
        const f16* pb = baseB[t2] + (size_t)(KC_) * 1024; \
        AH[t2] = *(const f16x8*)(pa); \
        AL[t2] = *(const f16x8*)(pa + 512); \
        BH[t2] = *(const f16x8*)(pb); \
        BL[t2] = *(const f16x8*)(pb + 512); \
    }

#define MFMA_SET(AH, AL, BH, BL) \
    _Pragma("unroll") \
    for (int mi = 0; mi < 4; ++mi) \
        _Pragma("unroll") \
        for (int ni = 0; ni < 4; ++ni) { \
            acc[mi][ni] = __builtin_amdgcn_mfma_f32_16x16x32_f16( \
                AH[mi], BH[ni], acc[mi][ni], 0, 0, 0); \
            acc[mi][ni] = __builtin_amdgcn_mfma_f32_16x16x32_f16( \
                AH[mi], BL[ni], acc[mi][ni], 0, 0, 0); \
            acc[mi][ni] = __builtin_amdgcn_mfma_f32_16x16x32_f16( \
                AL[mi], BH[ni], acc[mi][ni], 0, 0, 0); \
        }

    LOAD_SET(ah0, al0, bh0, bl0, 0)
    for (int kc = 0; kc < KC_COUNT; kc += 2) {
        LOAD_SET(ah1, al1, bh1, bl1, kc + 1)      // in flight during ping MFMA
        MFMA_SET(ah0, al0, bh0, bl0)
        if (kc + 2 < KC_COUNT) {
            LOAD_SET(ah0, al0, bh0, bl0, kc + 2)  // in flight during pong MFMA
        }
        MFMA_SET(ah1, al1, bh1, bl1)
    }
#undef LOAD_SET
#undef MFMA_SET

    // Epilogue. C/D layout (16x16): col = lane&15, row = (lane>>4)*4 + reg.
    const int g16 = lane >> 4, c16 = lane & 15;

    int ljv[4], liv[4][4];
#pragma unroll
    for (int ni = 0; ni < 4; ++ni) ljv[ni] = labels[colBase + wc * 64 + ni * 16 + c16];
#pragma unroll
    for (int mi = 0; mi < 4; ++mi)
#pragma unroll
        for (int reg = 0; reg < 4; ++reg)
            liv[mi][reg] = labels[rowBase + wr * 64 + mi * 16 + g16 * 4 + reg];

    // Pass 1: row-side argmin (rows of bi-range over cols of bj-range).
#pragma unroll
    for (int mi = 0; mi < 4; ++mi) {
#pragma unroll
        for (int reg = 0; reg < 4; ++reg) {
            const int rloc = wr * 64 + mi * 16 + g16 * 4 + reg;
            const int i = rowBase + rloc;
            const int li = liv[mi][reg];
            float bestAp = __builtin_huge_valf(); int jAp = 0;
            float bestAn = __builtin_huge_valf(); int jAn = 0;
#pragma unroll
            for (int ni = 0; ni < 4; ++ni) {
                const int jcol = colBase + wc * 64 + ni * 16 + c16;
                const float v = acc[mi][ni][reg];
                const bool same = (li == ljv[ni]);
                const float vap = (same && (i != jcol)) ? v : v + 2.0f;
                const float van = (!same) ? v : v + 2.0f;
                if (vap < bestAp) { bestAp = vap; jAp = jcol; }
                if (van < bestAn) { bestAn = van; jAn = jcol; }
            }
            unsigned long long kap =
                ((unsigned long long)orderable(bestAp) << 32) | (unsigned)jAp;
            unsigned long long kan =
                ((unsigned long long)orderable(bestAn) << 32) | (unsigned)jAn;
#pragma unroll
            for (int off = 1; off < 16; off <<= 1) {
                unsigned long long o = __shfl_xor(kap, off); kap = o < kap ? o : kap;
                o = __shfl_xor(kan, off); kan = o < kan ? o : kan;
            }
            if (c16 == 0) {
                atomicMin(&keys_ap[i], kap);
                atomicMin(&keys_an[i], kan);
            }
        }
    }

    // Pass 2 (off-diagonal only): column-side argmin via symmetry.
    if (bi != bj) {
#pragma unroll
        for (int ni = 0; ni < 4; ++ni) {
            const int j = colBase + wc * 64 + ni * 16 + c16;
            const int lj = ljv[ni];
            float bestAp = __builtin_huge_valf(); int iAp = 0;
            float bestAn = __builtin_huge_valf(); int iAn = 0;
#pragma unroll
            for (int mi = 0; mi < 4; ++mi)
#pragma unroll
                for (int reg = 0; reg < 4; ++reg) {
                    const int i = rowBase + wr * 64 + mi * 16 + g16 * 4 + reg;
                    const float v = acc[mi][ni][reg];
                    const bool same = (liv[mi][reg] == lj);
                    const float vap = same ? v : v + 2.0f;   // i != j off-diag
                    const float van = (!same) ? v : v + 2.0f;
                    if (vap < bestAp) { bestAp = vap; iAp = i; }
                    if (van < bestAn) { bestAn = van; iAn = i; }
                }
            unsigned long long kap =
                ((unsigned long long)orderable(bestAp) << 32) | (unsigned)iAp;
            unsigned long long kan =
                ((unsigned long long)orderable(bestAn) << 32) | (unsigned)iAn;
            // Reduce over g16 (lane bits 4,5): lanes sharing c16 share j.
#pragma unroll
            for (int off = 16; off < 64; off <<= 1) {
                unsigned long long o = __shfl_xor(kap, off); kap = o < kap ? o : kap;
                o = __shfl_xor(kan, off); kan = o < kan ? o : kan;
            }
            if (g16 == 0) {
                atomicMin(&keys_ap[j], kap);
                atomicMin(&keys_an[j], kan);
            }
        }
    }
}

__global__ void gather_rows(const float* __restrict__ A,
                            const unsigned long long* __restrict__ keys_ap,
                            const unsigned long long* __restrict__ keys_an,
                            float* __restrict__ out)
{
    const int row = blockIdx.x;
    const int t = threadIdx.x;
    const int ja = (int)(keys_ap[row] & 0xFFFFFFFFull);
    const int jn = (int)(keys_an[row] & 0xFFFFFFFFull);
    const float4* Av = (const float4*)A;
    float4* Ov = (float4*)out;
    Ov[(size_t)row * (D / 4) + t]       = Av[(size_t)ja * (D / 4) + t];
    Ov[(size_t)(N + row) * (D / 4) + t] = Av[(size_t)jn * (D / 4) + t];
}

extern "C" void kernel_launch(void* const* d_in, const int* in_sizes, int n_in,
                              void* d_out, int out_size, void* d_ws, size_t ws_size,
                              hipStream_t stream) {
    const float* A = (const float*)d_in[0];
    const int* labels = (const int*)d_in[1];  // integer inputs arrive as int32
    float* out = (float*)d_out;

    unsigned long long* keys = (unsigned long long*)d_ws;          // 64 KB
    f16* Xsw = (f16*)((char*)d_ws + 65536);                        // 16 MB hi+lo

    split_swizzle<<<N / 16, 256, 0, stream>>>(A, Xsw, keys);
    gemm_argmin_sym<<<NBLK, 256, 0, stream>>>(Xsw, labels, keys, keys + N);
    gather_rows<<<N, 256, 0, stream>>>(A, keys, keys + N, out);
}

// Round 9
// 174.149 us; speedup vs baseline: 1.1407x; 1.0179x over previous
//
#include <hip/hip_runtime.h>
#include <cstdint>

#define N 4096
#define D 1024
#define KC_COUNT (D / 32)   // 32 k-chunks of 32
#define TG (N / 64)         // 64 sub-tile rows/cols of 64
#define NWAVE (TG * (TG + 1) / 2)   // 2080 upper-triangular 64x64 sub-tiles

typedef _Float16 f16;
typedef __attribute__((ext_vector_type(4))) _Float16 f16x4;
typedef __attribute__((ext_vector_type(8))) _Float16 f16x8;
typedef __attribute__((ext_vector_type(4))) float f32x4;

// Monotone map fp32 -> u32 so unsigned compare == float compare (ascending).
__device__ __forceinline__ unsigned int orderable(float f) {
    unsigned int b = __float_as_uint(f);
    return (b & 0x80000000u) ? ~b : (b | 0x80000000u);
}

// Split fp32 X into f16 hi/lo planes pre-swizzled into MFMA fragment order:
// chunk (rg, kc, hl) holds 512 f16 ordered by lane=(q<<4)|m, elem=k&7, where
// row = rg*16+m, k = kc*32+q*8+elem. A lane's fragment = contiguous 16 B.
#define ROW_PAD 8
#define ROW_STRIDE (D + ROW_PAD)   // 2064 B rows: keeps ds_read_b128 aligned
__global__ __launch_bounds__(256) void split_swizzle(
    const float* __restrict__ X, f16* __restrict__ Xsw,
    unsigned long long* __restrict__ keys)
{
    __shared__ f16 Hs[16 * ROW_STRIDE];
    __shared__ f16 Ls[16 * ROW_STRIDE];
    const int tid = threadIdx.x;
    const int rg = blockIdx.x;                 // 0..255, 16 rows each
    if (tid < 32) keys[rg * 32 + tid] = 0xFFFFFFFFFFFFFFFFull;

    const float4* src = (const float4*)(X + (size_t)rg * 16 * D);
#pragma unroll
    for (int it = 0; it < 16; ++it) {
        const int idx4 = it * 256 + tid;       // 0..4095 float4 slots
        const int row = idx4 >> 8;
        const int k4 = (idx4 & 255) * 4;
        const float4 v = src[idx4];
        const float xs[4] = {v.x, v.y, v.z, v.w};
        f16x4 h, l;
#pragma unroll
        for (int i = 0; i < 4; ++i) {
            f16 hh = (f16)xs[i];
            h[i] = hh;
            l[i] = (f16)(xs[i] - (float)hh);
        }
        *(f16x4*)(Hs + row * ROW_STRIDE + k4) = h;
        *(f16x4*)(Ls + row * ROW_STRIDE + k4) = l;
    }
    __syncthreads();
#pragma unroll
    for (int hl = 0; hl < 2; ++hl) {
        const f16* lds = hl ? Ls : Hs;
#pragma unroll
        for (int it = 0; it < 8; ++it) {
            const int o = it * 256 + tid;      // uint4 slot among 2048
            const int kc = o >> 6, lo_ = o & 63;
            const int q = lo_ >> 4, m = lo_ & 15;
            const uint4 v = *(const uint4*)(lds + m * ROW_STRIDE + kc * 32 + q * 8);
            *(uint4*)(Xsw + (((size_t)rg * KC_COUNT + kc) * 2 + hl) * 512 + lo_ * 8) = v;
        }
    }
}

// One WAVE per 64x64 upper-triangular sub-tile of dist = X @ X^T.
// 2080 single-wave blocks, all co-resident (3 waves/SIMD at 136 VGPR):
// no dispatch tail, hardware interleaves diag/off-diag imbalance.
// f16-split MFMA (hi*hi + hi*lo + lo*hi), VGPR ping-pong, no LDS/barriers.
__global__ __launch_bounds__(64) void gemm_argmin_sym(
    const f16* __restrict__ Xsw, const int* __restrict__ labels,
    unsigned long long* __restrict__ keys_ap,
    unsigned long long* __restrict__ keys_an)
{
    // Decode linear id -> (ti, tj), ti <= tj, over TG=64 tile rows.
    int r = blockIdx.x;
    int ti = (int)((2.0f * TG + 1.0f -
                    sqrtf((2.0f * TG + 1.0f) * (2.0f * TG + 1.0f) - 8.0f * (float)r)) * 0.5f);
    // guard against fp rounding
    while (ti > 0 && r < ti * TG - ti * (ti - 1) / 2) --ti;
    while (r >= (ti + 1) * TG - ti * (ti + 1) / 2) ++ti;
    const int tj = ti + (r - (ti * TG - ti * (ti - 1) / 2));

    const int lane = threadIdx.x & 63;
    const int rowBase = ti * 64, colBase = tj * 64;

    f32x4 acc[4][4];
#pragma unroll
    for (int mi = 0; mi < 4; ++mi)
#pragma unroll
        for (int ni = 0; ni < 4; ++ni) acc[mi][ni] = (f32x4){0.f, 0.f, 0.f, 0.f};

    // Fragment base pointers (hi at +0, lo at +512; kc stride 1024 f16).
    const f16* baseA[4];
    const f16* baseB[4];
#pragma unroll
    for (int t2 = 0; t2 < 4; ++t2) {
        const int rgA = ti * 4 + t2;
        const int rgB = tj * 4 + t2;
        baseA[t2] = Xsw + ((size_t)rgA * KC_COUNT * 2) * 512 + lane * 8;
        baseB[t2] = Xsw + ((size_t)rgB * KC_COUNT * 2) * 512 + lane * 8;
    }

    f16x8 ah0[4], al0[4], bh0[4], bl0[4];   // ping
    f16x8 ah1[4], al1[4], bh1[4], bl1[4];   // pong

#define LOAD_SET(AH, AL, BH, BL, KC_) \
    _Pragma("unroll") \
    for (int t2 = 0; t2 < 4; ++t2) { \
        const f16* pa = baseA[t2] + (size_t)(KC_) * 1024; \
        const f16* pb = baseB[t2] + (size_t)(KC_) * 1024; \
        AH[t2] = *(const f16x8*)(pa); \
        AL[t2] = *(const f16x8*)(pa + 512); \
        BH[t2] = *(const f16x8*)(pb); \
        BL[t2] = *(const f16x8*)(pb + 512); \
    }

#define MFMA_SET(AH, AL, BH, BL) \
    _Pragma("unroll") \
    for (int mi = 0; mi < 4; ++mi) \
        _Pragma("unroll") \
        for (int ni = 0; ni < 4; ++ni) { \
            acc[mi][ni] = __builtin_amdgcn_mfma_f32_16x16x32_f16( \
                AH[mi], BH[ni], acc[mi][ni], 0, 0, 0); \
            acc[mi][ni] = __builtin_amdgcn_mfma_f32_16x16x32_f16( \
                AH[mi], BL[ni], acc[mi][ni], 0, 0, 0); \
            acc[mi][ni] = __builtin_amdgcn_mfma_f32_16x16x32_f16( \
                AL[mi], BH[ni], acc[mi][ni], 0, 0, 0); \
        }

    LOAD_SET(ah0, al0, bh0, bl0, 0)
    for (int kc = 0; kc < KC_COUNT; kc += 2) {
        LOAD_SET(ah1, al1, bh1, bl1, kc + 1)      // in flight during ping MFMA
        MFMA_SET(ah0, al0, bh0, bl0)
        if (kc + 2 < KC_COUNT) {
            LOAD_SET(ah0, al0, bh0, bl0, kc + 2)  // in flight during pong MFMA
        }
        MFMA_SET(ah1, al1, bh1, bl1)
    }
#undef LOAD_SET
#undef MFMA_SET

    // Epilogue. C/D layout (16x16): col = lane&15, row = (lane>>4)*4 + reg.
    const int g16 = lane >> 4, c16 = lane & 15;

    int ljv[4], liv[4][4];
#pragma unroll
    for (int ni = 0; ni < 4; ++ni) ljv[ni] = labels[colBase + ni * 16 + c16];
#pragma unroll
    for (int mi = 0; mi < 4; ++mi)
#pragma unroll
        for (int reg = 0; reg < 4; ++reg)
            liv[mi][reg] = labels[rowBase + mi * 16 + g16 * 4 + reg];

    // Pass 1: row-side argmin (rows of ti-range over cols of tj-range).
#pragma unroll
    for (int mi = 0; mi < 4; ++mi) {
#pragma unroll
        for (int reg = 0; reg < 4; ++reg) {
            const int i = rowBase + mi * 16 + g16 * 4 + reg;
            const int li = liv[mi][reg];
            float bestAp = __builtin_huge_valf(); int jAp = 0;
            float bestAn = __builtin_huge_valf(); int jAn = 0;
#pragma unroll
            for (int ni = 0; ni < 4; ++ni) {
                const int jcol = colBase + ni * 16 + c16;
                const float v = acc[mi][ni][reg];
                const bool same = (li == ljv[ni]);
                const float vap = (same && (i != jcol)) ? v : v + 2.0f;
                const float van = (!same) ? v : v + 2.0f;
                if (vap < bestAp) { bestAp = vap; jAp = jcol; }
                if (van < bestAn) { bestAn = van; jAn = jcol; }
            }
            unsigned long long kap =
                ((unsigned long long)orderable(bestAp) << 32) | (unsigned)jAp;
            unsigned long long kan =
                ((unsigned long long)orderable(bestAn) << 32) | (unsigned)jAn;
#pragma unroll
            for (int off = 1; off < 16; off <<= 1) {
                unsigned long long o = __shfl_xor(kap, off); kap = o < kap ? o : kap;
                o = __shfl_xor(kan, off); kan = o < kan ? o : kan;
            }
            if (c16 == 0) {
                atomicMin(&keys_ap[i], kap);
                atomicMin(&keys_an[i], kan);
            }
        }
    }

    // Pass 2 (off-diagonal only): column-side argmin via symmetry.
    if (ti != tj) {
#pragma unroll
        for (int ni = 0; ni < 4; ++ni) {
            const int j = colBase + ni * 16 + c16;
            const int lj = ljv[ni];
            float bestAp = __builtin_huge_valf(); int iAp = 0;
            float bestAn = __builtin_huge_valf(); int iAn = 0;
#pragma unroll
            for (int mi = 0; mi < 4; ++mi)
#pragma unroll
                for (int reg = 0; reg < 4; ++reg) {
                    const int i = rowBase + mi * 16 + g16 * 4 + reg;
                    const float v = acc[mi][ni][reg];
                    const bool same = (liv[mi][reg] == lj);
                    const float vap = same ? v : v + 2.0f;   // i != j off-diag
                    const float van = (!same) ? v : v + 2.0f;
                    if (vap < bestAp) { bestAp = vap; iAp = i; }
                    if (van < bestAn) { bestAn = van; iAn = i; }
                }
            unsigned long long kap =
                ((unsigned long long)orderable(bestAp) << 32) | (unsigned)iAp;
            unsigned long long kan =
                ((unsigned long long)orderable(bestAn) << 32) | (unsigned)iAn;
            // Reduce over g16 (lane bits 4,5): lanes sharing c16 share j.
#pragma unroll
            for (int off = 16; off < 64; off <<= 1) {
                unsigned long long o = __shfl_xor(kap, off); kap = o < kap ? o : kap;
                o = __shfl_xor(kan, off); kan = o < kan ? o : kan;
            }
            if (g16 == 0) {
                atomicMin(&keys_ap[j], kap);
                atomicMin(&keys_an[j], kan);
            }
        }
    }
}

__global__ void gather_rows(const float* __restrict__ A,
                            const unsigned long long* __restrict__ keys_ap,
                            const unsigned long long* __restrict__ keys_an,
                            float* __restrict__ out)
{
    const int row = blockIdx.x;
    const int t = threadIdx.x;
    const int ja = (int)(keys_ap[row] & 0xFFFFFFFFull);
    const int jn = (int)(keys_an[row] & 0xFFFFFFFFull);
    const float4* Av = (const float4*)A;
    float4* Ov = (float4*)out;
    Ov[(size_t)row * (D / 4) + t]       = Av[(size_t)ja * (D / 4) + t];
    Ov[(size_t)(N + row) * (D / 4) + t] = Av[(size_t)jn * (D / 4) + t];
}

extern "C" void kernel_launch(void* const* d_in, const int* in_sizes, int n_in,
                              void* d_out, int out_size, void* d_ws, size_t ws_size,
                              hipStream_t stream) {
    const float* A = (const float*)d_in[0];
    const int* labels = (const int*)d_in[1];  // integer inputs arrive as int32
    float* out = (float*)d_out;

    unsigned long long* keys = (unsigned long long*)d_ws;          // 64 KB
    f16* Xsw = (f16*)((char*)d_ws + 65536);                        // 16 MB hi+lo

    split_swizzle<<<N / 16, 256, 0, stream>>>(A, Xsw, keys);
    gemm_argmin_sym<<<NWAVE, 64, 0, stream>>>(Xsw, labels, keys, keys + N);
    gather_rows<<<N, 256, 0, stream>>>(A, keys, keys + N, out);
}

// Round 10
// 155.187 us; speedup vs baseline: 1.2801x; 1.1222x over previous
//
#include <hip/hip_runtime.h>
#include <cstdint>

#define N 4096
#define D 1024
#define KC_COUNT (D / 32)    // 32 k-chunks of 32
#define NP 4128              // N padded to a multiple of 96
#define RGP (NP / 16)        // 258 row-groups of 16 in Xsw
#define TG (NP / 96)         // 43 tile rows/cols of 96
#define NBLK (TG * (TG + 1) / 2)   // 946 upper-triangular 96x96 tiles

typedef _Float16 f16;
typedef __attribute__((ext_vector_type(4))) _Float16 f16x4;
typedef __attribute__((ext_vector_type(8))) _Float16 f16x8;
typedef __attribute__((ext_vector_type(4))) float f32x4;

// Monotone map fp32 -> u32 so unsigned compare == float compare (ascending).
__device__ __forceinline__ unsigned int orderable(float f) {
    unsigned int b = __float_as_uint(f);
    return (b & 0x80000000u) ? ~b : (b | 0x80000000u);
}

__device__ __forceinline__ void async_copy16(const f16* g, f16* l) {
    __builtin_amdgcn_global_load_lds(
        (const __attribute__((address_space(1))) uint32_t*)(const void*)g,
        (__attribute__((address_space(3))) uint32_t*)(void*)l,
        16 /*bytes*/, 0 /*offset*/, 0 /*aux*/);
}

// Split fp32 X into f16 hi/lo planes pre-swizzled into MFMA fragment order:
// chunk (rg, kc, hl) holds 512 f16 ordered by lane=(q<<4)|m, elem=k&7, where
// row = rg*16+m, k = kc*32+q*8+elem. 1032 blocks: rg 0..257 x kquarter 0..3.
// rg >= 256 are zero pad rows. LDS stride 280 f16 = 140 dw == 12 mod 32:
// phase-2 b128 reads are 2-way-conflict (free), 16B-aligned.
#define KSPAN 256
#define SS_STRIDE (KSPAN + 24)   // 280 f16 = 560 B
__global__ __launch_bounds__(256) void split_swizzle(
    const float* __restrict__ X, f16* __restrict__ Xsw,
    unsigned long long* __restrict__ keys)
{
    __shared__ f16 Hs[16 * SS_STRIDE];
    __shared__ f16 Ls[16 * SS_STRIDE];
    const int tid = threadIdx.x;
    const int bid = blockIdx.x;
    const int rg = bid >> 2, kq = bid & 3;
    if (bid < 32) keys[bid * 256 + tid] = 0xFFFFFFFFFFFFFFFFull;

    if (rg >= 256) {   // zero pad rows 4096..4127
        const uint4 z = {0, 0, 0, 0};
#pragma unroll
        for (int i = 0; i < 4; ++i) {
            const int o = i * 256 + tid;               // 1024 uint4 slots
            const int kcl = o >> 7, rem = o & 127;     // kcl 0..7, rem: hl*64+lo_
            const int kc = kq * 8 + kcl;
            *(uint4*)(Xsw + (((size_t)rg * KC_COUNT + kc) * 2) * 512 + rem * 8) = z;
        }
        return;
    }

    // Phase 1: coalesced fp32 read -> split -> LDS row-major.
#pragma unroll
    for (int i = 0; i < 4; ++i) {
        const int idx4 = i * 256 + tid;        // 1024 float4 slots
        const int row = idx4 >> 6, c4 = idx4 & 63;
        const float4 v = *(const float4*)(X + (size_t)(rg * 16 + row) * D + kq * KSPAN + c4 * 4);
        const float xs[4] = {v.x, v.y, v.z, v.w};
        f16x4 h, l;
#pragma unroll
        for (int e = 0; e < 4; ++e) {
            f16 hh = (f16)xs[e];
            h[e] = hh;
            l[e] = (f16)(xs[e] - (float)hh);
        }
        *(f16x4*)(Hs + row * SS_STRIDE + c4 * 4) = h;
        *(f16x4*)(Ls + row * SS_STRIDE + c4 * 4) = l;
    }
    __syncthreads();

    // Phase 2: swizzled b128 LDS reads -> coalesced global stores.
#pragma unroll
    for (int hl = 0; hl < 2; ++hl) {
        const f16* lds = hl ? Ls : Hs;
#pragma unroll
        for (int i = 0; i < 2; ++i) {
            const int o = i * 256 + tid;       // 512 uint4 slots
            const int kcl = o >> 6, lo_ = o & 63;
            const int q = lo_ >> 4, m = lo_ & 15;
            const uint4 v = *(const uint4*)(lds + m * SS_STRIDE + kcl * 32 + q * 8);
            const int kc = kq * 8 + kcl;
            *(uint4*)(Xsw + (((size_t)rg * KC_COUNT + kc) * 2 + hl) * 512 + lo_ * 8) = v;
        }
    }
}

// 96x96 upper-triangular tile of dist = X @ X^T, 4 waves (2x2 of 48x48),
// f16-split MFMA (hi*hi + hi*lo + lo*hi), R3-style single-buffer 2-barrier
// LDS loop. 946 blocks ~ 3.7/CU fully co-resident: cross-block interleaving
// hides the barrier drains (the empirically best regime, R3).
__global__ __launch_bounds__(256, 4) void gemm_argmin_sym(
    const f16* __restrict__ Xsw, const int* __restrict__ labels,
    unsigned long long* __restrict__ keys_ap,
    unsigned long long* __restrict__ keys_an)
{
    __shared__ f16 As[6 * 2 * 512];   // [rgLocal(6)][hl(2)][lane(64)][8] = 12 KB
    __shared__ f16 Bs[6 * 2 * 512];   // 12 KB

    // Decode linear block id -> (ti, tj) with ti <= tj over TG=43.
    int r = blockIdx.x, ti = 0;
    while (r >= TG - ti) { r -= TG - ti; ++ti; }
    const int tj = ti + r;

    const int tid = threadIdx.x;
    const int lane = tid & 63;
    const int w = tid >> 6;            // wave 0..3
    const int wr = w >> 1, wc = w & 1; // 2x2 wave grid, 48x48 region each
    const int rowBase = ti * 96, colBase = tj * 96;

    f32x4 acc[3][3];
#pragma unroll
    for (int mi = 0; mi < 3; ++mi)
#pragma unroll
        for (int ni = 0; ni < 3; ++ni) acc[mi][ni] = (f32x4){0.f, 0.f, 0.f, 0.f};

    // Wave w stages chunks c = w*6 .. w*6+5 (24 total: A/B x 6rg x hi/lo).
    const f16* g[6];
    f16* lp[6];
#pragma unroll
    for (int j = 0; j < 6; ++j) {
        int c = w * 6 + j;
        int isB = c >= 12, rem = isB ? c - 12 : c, rgL = rem >> 1, hl = rem & 1;
        int rgG = (isB ? tj : ti) * 6 + rgL;
        g[j] = Xsw + ((((size_t)rgG * KC_COUNT) * 2 + hl) * 64 + lane) * 8;  // kc=0
        lp[j] = (isB ? Bs : As) + (rgL * 2 + hl) * 512;  // wave-uniform base
    }

    for (int kc = 0; kc < KC_COUNT; ++kc) {
#pragma unroll
        for (int j = 0; j < 6; ++j)
            async_copy16(g[j] + (size_t)kc * 1024, lp[j]);
        __syncthreads();   // drain: tile ready

        f16x8 ah[3], al[3], bh[3], bl[3];
#pragma unroll
        for (int t2 = 0; t2 < 3; ++t2) {
            int rgA = wr * 3 + t2, rgB = wc * 3 + t2;
            ah[t2] = *(const f16x8*)(As + (rgA * 2 + 0) * 512 + lane * 8);
            al[t2] = *(const f16x8*)(As + (rgA * 2 + 1) * 512 + lane * 8);
            bh[t2] = *(const f16x8*)(Bs + (rgB * 2 + 0) * 512 + lane * 8);
            bl[t2] = *(const f16x8*)(Bs + (rgB * 2 + 1) * 512 + lane * 8);
        }
#pragma unroll
        for (int mi = 0; mi < 3; ++mi)
#pragma unroll
            for (int ni = 0; ni < 3; ++ni) {
                acc[mi][ni] = __builtin_amdgcn_mfma_f32_16x16x32_f16(
                    ah[mi], bh[ni], acc[mi][ni], 0, 0, 0);
                acc[mi][ni] = __builtin_amdgcn_mfma_f32_16x16x32_f16(
                    ah[mi], bl[ni], acc[mi][ni], 0, 0, 0);
                acc[mi][ni] = __builtin_amdgcn_mfma_f32_16x16x32_f16(
                    al[mi], bh[ni], acc[mi][ni], 0, 0, 0);
            }
        __syncthreads();   // all reads done before next stage overwrites
    }

    // Epilogue. C/D layout (16x16): col = lane&15, row = (lane>>4)*4 + reg.
    const int g16 = lane >> 4, c16 = lane & 15;

    int ljv[3], liv[3][4];
#pragma unroll
    for (int ni = 0; ni < 3; ++ni) {
        const int j = colBase + wc * 48 + ni * 16 + c16;
        ljv[ni] = (j < N) ? labels[j] : -1;    // pad sentinel: matches nothing
    }
#pragma unroll
    for (int mi = 0; mi < 3; ++mi)
#pragma unroll
        for (int reg = 0; reg < 4; ++reg) {
            const int i = rowBase + wr * 48 + mi * 16 + g16 * 4 + reg;
            liv[mi][reg] = (i < N) ? labels[i] : -1;
        }

    // Pass 1: row-side argmin (rows of ti-range over cols of tj-range).
#pragma unroll
    for (int mi = 0; mi < 3; ++mi) {
#pragma unroll
        for (int reg = 0; reg < 4; ++reg) {
            const int i = rowBase + wr * 48 + mi * 16 + g16 * 4 + reg;
            const int li = liv[mi][reg];
            float bestAp = __builtin_huge_valf(); int jAp = 0;
            float bestAn = __builtin_huge_valf(); int jAn = 0;
#pragma unroll
            for (int ni = 0; ni < 3; ++ni) {
                const int jcol = colBase + wc * 48 + ni * 16 + c16;
                const float v = acc[mi][ni][reg];
                const bool same = (li == ljv[ni]);
                const float vap = (same && (i != jcol)) ? v : v + 2.0f;
                const float van = (!same) ? v : v + 2.0f;
                if (vap < bestAp) { bestAp = vap; jAp = jcol; }
                if (van < bestAn) { bestAn = van; jAn = jcol; }
            }
            unsigned long long kap =
                ((unsigned long long)orderable(bestAp) << 32) | (unsigned)jAp;
            unsigned long long kan =
                ((unsigned long long)orderable(bestAn) << 32) | (unsigned)jAn;
#pragma unroll
            for (int off = 1; off < 16; off <<= 1) {
                unsigned long long o = __shfl_xor(kap, off); kap = o < kap ? o : kap;
                o = __shfl_xor(kan, off); kan = o < kan ? o : kan;
            }
            if (c16 == 0 && i < N) {
                atomicMin(&keys_ap[i], kap);
                atomicMin(&keys_an[i], kan);
            }
        }
    }

    // Pass 2 (off-diagonal only): column-side argmin via symmetry.
    if (ti != tj) {
#pragma unroll
        for (int ni = 0; ni < 3; ++ni) {
            const int j = colBase + wc * 48 + ni * 16 + c16;
            const int lj = ljv[ni];
            float bestAp = __builtin_huge_valf(); int iAp = 0;
            float bestAn = __builtin_huge_valf(); int iAn = 0;
#pragma unroll
            for (int mi = 0; mi < 3; ++mi)
#pragma unroll
                for (int reg = 0; reg < 4; ++reg) {
                    const int i = rowBase + wr * 48 + mi * 16 + g16 * 4 + reg;
                    const float v = acc[mi][ni][reg];
                    // pad rows have label -1 != lj -> negative, v = 0: never wins
                    const bool same = (liv[mi][reg] == lj);
                    const float vap = same ? v : v + 2.0f;   // i != j off-diag
                    const float van = (!same) ? v : v + 2.0f;
                    if (vap < bestAp) { bestAp = vap; iAp = i; }
                    if (van < bestAn) { bestAn = van; iAn = i; }
                }
            unsigned long long kap =
                ((unsigned long long)orderable(bestAp) << 32) | (unsigned)iAp;
            unsigned long long kan =
                ((unsigned long long)orderable(bestAn) << 32) | (unsigned)iAn;
            // Reduce over g16 (lane bits 4,5): lanes sharing c16 share j.
#pragma unroll
            for (int off = 16; off < 64; off <<= 1) {
                unsigned long long o = __shfl_xor(kap, off); kap = o < kap ? o : kap;
                o = __shfl_xor(kan, off); kan = o < kan ? o : kan;
            }
            if (g16 == 0 && j < N) {
                atomicMin(&keys_ap[j], kap);
                atomicMin(&keys_an[j], kan);
            }
        }
    }
}

__global__ void gather_rows(const float* __restrict__ A,
                            const unsigned long long* __restrict__ keys_ap,
                            const unsigned long long* __restrict__ keys_an,
                            float* __restrict__ out)
{
    const int row = blockIdx.x;
    const int t = threadIdx.x;
    const int ja = (int)(keys_ap[row] & 0xFFFFFFFFull);
    const int jn = (int)(keys_an[row] & 0xFFFFFFFFull);
    const float4* Av = (const float4*)A;
    float4* Ov = (float4*)out;
    Ov[(size_t)row * (D / 4) + t]       = Av[(size_t)ja * (D / 4) + t];
    Ov[(size_t)(N + row) * (D / 4) + t] = Av[(size_t)jn * (D / 4) + t];
}

extern "C" void kernel_launch(void* const* d_in, const int* in_sizes, int n_in,
                              void* d_out, int out_size, void* d_ws, size_t ws_size,
                              hipStream_t stream) {
    const float* A = (const float*)d_in[0];
    const int* labels = (const int*)d_in[1];  // integer inputs arrive as int32
    float* out = (float*)d_out;

    unsigned long long* keys = (unsigned long long*)d_ws;          // 64 KB
    f16* Xsw = (f16*)((char*)d_ws + 65536);   // 258 rg * 64 KB = 16.9 MB hi+lo

    split_swizzle<<<RGP * 4, 256, 0, stream>>>(A, Xsw, keys);
    gemm_argmin_sym<<<NBLK, 256, 0, stream>>>(Xsw, labels, keys, keys + N);
    gather_rows<<<N, 256, 0, stream>>>(A, keys, keys + N, out);
}